// Round 4
// baseline (881.736 us; speedup 1.0000x reference)
//
#include <hip/hip_runtime.h>

constexpr int NN = 50000;     // nodes
constexpr int NE = 800000;    // edges
constexpr float SLOPE_A = 0.2f;   // attention leaky_relu
constexpr float SLOPE_R = 0.01f;  // activation leaky_relu
constexpr int SCB = 196;      // scan blocks: 196*256 = 50176 >= NN

typedef __attribute__((ext_vector_type(8))) short bf16x8;
typedef __attribute__((ext_vector_type(4))) float f32x4;

__device__ __forceinline__ unsigned short f2bf(float f) {
    union { float f; unsigned u; } v; v.f = f;
    unsigned u = v.u;
    unsigned r = u + 0x7fffu + ((u >> 16) & 1u);  // round-to-nearest-even
    return (unsigned short)(r >> 16);
}
__device__ __forceinline__ float bf2f(unsigned short s) {
    union { unsigned u; float f; } v; v.u = ((unsigned)s) << 16;
    return v.f;
}
// low/high bf16 halves of a packed u32 -> f32 (1 VALU op each)
__device__ __forceinline__ float bflo(unsigned u) {
    union { unsigned u; float f; } v; v.u = u << 16; return v.f;
}
__device__ __forceinline__ float bfhi(unsigned u) {
    union { unsigned u; float f; } v; v.u = u & 0xffff0000u; return v.f;
}

// ---------------- CSR build ----------------
__global__ void k_hist(const int* __restrict__ dst, int* __restrict__ cnt) {
    int i = blockIdx.x * 256 + threadIdx.x;
    if (i < NE) atomicAdd(&cnt[dst[i]], 1);
}

__global__ void k_scan1(const int* __restrict__ cnt, int* __restrict__ loc,
                        int* __restrict__ bsum) {
    __shared__ int sh[256];
    int t = threadIdx.x;
    int i = blockIdx.x * 256 + t;
    int v = (i < NN) ? cnt[i] : 0;
    sh[t] = v;
    __syncthreads();
    for (int off = 1; off < 256; off <<= 1) {
        int tmp = (t >= off) ? sh[t - off] : 0;
        __syncthreads();
        sh[t] += tmp;
        __syncthreads();
    }
    loc[i] = sh[t] - v;
    if (t == 255) bsum[blockIdx.x] = sh[255];
}

__global__ void k_scan2(const int* __restrict__ bsum, int* __restrict__ boff,
                        int* __restrict__ rowptr) {
    __shared__ int sh[256];
    int t = threadIdx.x;
    int v = (t < SCB) ? bsum[t] : 0;
    sh[t] = v;
    __syncthreads();
    for (int off = 1; off < 256; off <<= 1) {
        int tmp = (t >= off) ? sh[t - off] : 0;
        __syncthreads();
        sh[t] += tmp;
        __syncthreads();
    }
    if (t < SCB) boff[t] = sh[t] - v;
    if (t == 255) rowptr[NN] = sh[255];
}

__global__ void k_scan3(const int* __restrict__ loc, const int* __restrict__ boff,
                        int* __restrict__ rowptr, int* __restrict__ cursor) {
    int i = blockIdx.x * 256 + threadIdx.x;
    if (i < NN) {
        int r = loc[i] + boff[blockIdx.x];
        rowptr[i] = r;
        cursor[i] = r;
    }
}

// src ids fit in 16 bits (NN < 65536): halves the sorted-src stream
__global__ void k_scatter(const int* __restrict__ src, const int* __restrict__ dst,
                          int* __restrict__ cursor, unsigned short* __restrict__ ssrc) {
    int i = blockIdx.x * 256 + threadIdx.x;
    if (i < NE) {
        int d = dst[i];
        int pos = atomicAdd(&cursor[d], 1);
        ssrc[pos] = (unsigned short)src[i];
    }
}

// ---------------- fold: Wfrag + cvec + wl/wr fragment + offlr, all from fp32 W ----
// has_bn=1 grid 296: b<32 Wfrag | 32..287 cvec | 288..295 lr-fold (n=b-288)
// has_bn=0 grid  40: b<32 Wfrag | 32..39 lr-fold (n=b-32)
__global__ void k_fold(const float* __restrict__ W, const float* __restrict__ sc,
                       const float* __restrict__ sh, const float* __restrict__ al,
                       const float* __restrict__ ar, unsigned short* __restrict__ Wfrag,
                       float* __restrict__ cvec, unsigned short* __restrict__ wlrfrag,
                       float* __restrict__ offlr, int has_bn) {
    int b = blockIdx.x;
    if (b < 32) {
        int gid = b * 256 + threadIdx.x;   // < 8192; one thread = 8 shorts
        int lane = gid & 63;
        int frag = gid >> 6;               // 0..127
        int j = frag & 3, kc = (frag >> 2) & 7, w = frag >> 5;
        int mm = lane & 15, q = lane >> 4;
        int n = 64 * w + 16 * j + mm;
        int k0 = kc * 32 + q * 8;
        unsigned short o[8];
#pragma unroll
        for (int t = 0; t < 8; t++) {
            float wv = W[(size_t)(k0 + t) * 256 + n];
            if (sc) wv *= sc[k0 + t];
            o[t] = f2bf(wv);
        }
        *(uint4*)(Wfrag + (size_t)gid * 8) = *(const uint4*)o;
    } else if (has_bn && b < 288) {
        __shared__ float red[256];
        int n = b - 32, k = threadIdx.x;
        red[k] = sh[k] * W[(size_t)k * 256 + n];
        __syncthreads();
        for (int off = 128; off > 0; off >>= 1) {
            if (k < off) red[k] += red[k + off];
            __syncthreads();
        }
        if (k == 0) cvec[n] = red[0];
    } else {
        int n = b - (has_bn ? 288 : 32);   // 0..7
        int h = n >> 1;
        const float* a = (n & 1) ? ar : al;
        int k = threadIdx.x;
        float raw = 0.f;
#pragma unroll 8
        for (int d = 0; d < 64; d++)
            raw += W[(size_t)k * 256 + 64 * h + d] * a[h * 64 + d];
        float val = (sc ? sc[k] : 1.f) * raw;
        int kc = k >> 5, rem = k & 31, q = rem >> 3, t = rem & 7;  // k = kc*32+q*8+t
        wlrfrag[kc * 512 + (q * 16 + n) * 8 + t] = f2bf(val);
        wlrfrag[kc * 512 + (q * 16 + n + 8) * 8 + t] = 0;   // zero the unused col
        __shared__ float red[256];
        red[k] = sh ? sh[k] * raw : 0.f;
        __syncthreads();
        for (int off = 128; off > 0; off >>= 1) {
            if (k < off) red[k] += red[k + off];
            __syncthreads();
        }
        if (k == 0) offlr[n] = red[0];
    }
}

// ---------------- GEMM: feat = A @ Wfrag (+cvec); el/er via extra MFMA --------
// block: 256 thr = 4 waves; tile 64 rows x 256 cols; wave w owns cols [64w,64w+64).
// Wave 0 additionally computes the 8-col el/er matvec with one extra B-frag.
// el/er are stored HEAD-MAJOR ([h][NN]) so each XCD slice caches only 200 KB.
__launch_bounds__(256)
__global__ void k_gemm(const void* __restrict__ Araw, int af32,
                       const unsigned short* __restrict__ Wfrag,
                       const float* __restrict__ cvec,
                       const unsigned short* __restrict__ wlrfrag,
                       const float* __restrict__ offlr,
                       unsigned short* __restrict__ feat16, float* __restrict__ el,
                       float* __restrict__ er) {
    constexpr int AP = 264;  // A lds pitch in bf16 elems (row start 16B-aligned)
    __shared__ __align__(16) unsigned short Alds[64 * AP];
    const int tid = threadIdx.x;
    const int rowbase = blockIdx.x * 64;

    // stage A: 64 rows x 256 bf16
    if (af32) {
        const float* A = (const float*)Araw;
        int r = tid >> 6;
        int c4 = tid & 63;
        for (int it = 0; it < 16; it++) {
            int rr = it * 4 + r;
            int gr = rowbase + rr;
            float4 v = make_float4(0.f, 0.f, 0.f, 0.f);
            if (gr < NN) v = *(const float4*)(A + (size_t)gr * 256 + c4 * 4);
            ushort4 pv;
            pv.x = f2bf(v.x); pv.y = f2bf(v.y); pv.z = f2bf(v.z); pv.w = f2bf(v.w);
            *(ushort4*)(&Alds[rr * AP + c4 * 4]) = pv;
        }
    } else {
        const unsigned short* A = (const unsigned short*)Araw;
        for (int it = 0; it < 8; it++) {
            int idx = it * 256 + tid;
            int rr = idx >> 5;
            int c16 = idx & 31;
            int gr = rowbase + rr;
            uint4 v = make_uint4(0u, 0u, 0u, 0u);
            if (gr < NN) v = *(const uint4*)(A + (size_t)gr * 256 + c16 * 8);
            *(uint4*)(&Alds[rr * AP + c16 * 8]) = v;
        }
    }
    __syncthreads();

    f32x4 acc[4][4];
    for (int i = 0; i < 4; i++)
        for (int j = 0; j < 4; j++)
            acc[i][j] = (f32x4){0.f, 0.f, 0.f, 0.f};
    f32x4 accLR[4];
    for (int i = 0; i < 4; i++) accLR[i] = (f32x4){0.f, 0.f, 0.f, 0.f};

    const int lane = tid & 63, w = tid >> 6;
    const int mm = lane & 15, q = lane >> 4;

    const unsigned short* bbase = Wfrag + ((size_t)w * 8 * 4) * 512 + (size_t)lane * 8;

#pragma unroll
    for (int kc = 0; kc < 8; kc++) {
        bf16x8 a[4], b[4];
        for (int i = 0; i < 4; i++)
            a[i] = *(const bf16x8*)(&Alds[(16 * i + mm) * AP + kc * 32 + q * 8]);
        for (int j = 0; j < 4; j++)
            b[j] = *(const bf16x8*)(bbase + (size_t)(kc * 4 + j) * 512);
        for (int i = 0; i < 4; i++)
            for (int j = 0; j < 4; j++)
                acc[i][j] = __builtin_amdgcn_mfma_f32_16x16x32_bf16(a[i], b[j], acc[i][j], 0, 0, 0);
        if (w == 0) {
            bf16x8 blr = *(const bf16x8*)(wlrfrag + kc * 512 + lane * 8);
            for (int i = 0; i < 4; i++)
                accLR[i] = __builtin_amdgcn_mfma_f32_16x16x32_bf16(a[i], blr, accLR[i], 0, 0, 0);
        }
    }
    __syncthreads();   // all waves done reading Alds before epilogue reuses it

    // ---- folded-BN column offset on feat ----
    if (cvec) {
        float cv[4];
        for (int j = 0; j < 4; j++) cv[j] = cvec[64 * w + 16 * j + mm];
        for (int i = 0; i < 4; i++)
            for (int j = 0; j < 4; j++)
                for (int r = 0; r < 4; r++)
                    acc[i][j][r] += cv[j];
    }

    // ---- el/er write (wave 0, C-layout col=mm -> n=2h+s); head-major layout ----
    if (w == 0 && mm < 8) {
        float off = offlr[mm];
        int h = mm >> 1;
        float* dstp = (mm & 1) ? er : el;
        for (int i = 0; i < 4; i++)
            for (int r = 0; r < 4; r++) {
                int gr = rowbase + 16 * i + q * 4 + r;
                if (gr < NN) dstp[h * NN + gr] = accLR[i][r] + off;
            }
    }

    // ---- LDS-bounce feat16 store (C/D layout: col=lane&15, row=(lane>>4)*4+reg) ----
    for (int i = 0; i < 4; i++)
        for (int j = 0; j < 4; j++) {
            int gc = 64 * w + 16 * j + mm;
            for (int r = 0; r < 4; r++) {
                int rr = 16 * i + q * 4 + r;
                Alds[rr * AP + gc] = f2bf(acc[i][j][r]);
            }
        }
    __syncthreads();
    for (int it = 0; it < 8; it++) {
        int idx = it * 256 + tid;
        int rr = idx >> 5;
        int c16 = idx & 31;
        int gr = rowbase + rr;
        if (gr < NN)
            *(uint4*)(feat16 + (size_t)gr * 256 + c16 * 8) = *(const uint4*)(&Alds[rr * AP + c16 * 8]);
    }
}

// ---------------- XCD-sliced softmax + aggregation ----------------
// Grid = 8 slices x 3125 node-groups; block b -> slice b&7. Workgroups are
// dispatched round-robin across the 8 XCDs, so slice s runs (mostly) on XCD s
// and that XCD's L2 only ever sees a 3.2 MB feat16 column slice (+200 KB el
// head table) -> gathers become L2 hits instead of 3.7 TB/s L2-miss traffic.
// Slice = 32 channels = 64 B = one cache line per edge; one head per slice.
// Lane l: node j=l>>4 (4 nodes/wave), r=l&15: es=r>>2 edge-subset, ck=r&3
// 16B chunk. Per 16-edge step each lane has 4 independent gathers in flight.
// Edge-subset reduction via shfl_xor(4|8) AFTER the loop (off the issue path).
__launch_bounds__(256)
__global__ void k_aggs(const unsigned short* __restrict__ feat16,
                       const float* __restrict__ el, const float* __restrict__ er,
                       const int* __restrict__ rowptr, const unsigned short* __restrict__ ssrc,
                       const unsigned short* __restrict__ residh, const float* __restrict__ residf,
                       const float* __restrict__ bnscale, const float* __restrict__ bnshift,
                       int use_bn, const float* __restrict__ bias, int act,
                       unsigned short* __restrict__ outh, float* __restrict__ outf,
                       int final_mean) {
    int b = blockIdx.x;
    int slice = b & 7;             // -> XCD (perf heuristic only; correct regardless)
    int ng = b >> 3;               // node group of 16
    int l = threadIdx.x & 63;
    int w = threadIdx.x >> 6;
    int j = l >> 4;                // node within wave
    int r = l & 15;
    int es = r >> 2;               // edge subset (mod-4 class)
    int ck = r & 3;                // 16B chunk within the 64B slice
    int n = ng * 16 + w * 4 + j;   // < 50000 exactly
    int h = slice >> 1;            // head of this slice
    int coff = slice * 32 + ck * 8;  // channel offset of this lane's 8 channels

    int beg = rowptr[n], end = rowptr[n + 1];
    float er_h = er[h * NN + n];
    const float* elh = el + h * NN;

    float d = 0.f;
    float acc[8];
#pragma unroll
    for (int k = 0; k < 8; k++) acc[k] = 0.f;

    for (int e0 = beg; e0 < end; e0 += 16) {
        int ss[4];
#pragma unroll
        for (int t = 0; t < 4; t++) {
            int idx = e0 + t * 4 + es;
            ss[t] = ssrc[(idx < end) ? idx : beg];
        }
        float aa[4];
#pragma unroll
        for (int t = 0; t < 4; t++) aa[t] = elh[ss[t]];
        uint4 ff[4];
#pragma unroll
        for (int t = 0; t < 4; t++)
            ff[t] = *(const uint4*)(feat16 + (size_t)ss[t] * 256 + coff);
#pragma unroll
        for (int t = 0; t < 4; t++) {
            int idx = e0 + t * 4 + es;
            float sc = aa[t] + er_h;
            sc = (sc > 0.f) ? sc : SLOPE_A * sc;
            float wg = (idx < end) ? __expf(sc) : 0.f;
            d += wg;
            acc[0] += bflo(ff[t].x) * wg; acc[1] += bfhi(ff[t].x) * wg;
            acc[2] += bflo(ff[t].y) * wg; acc[3] += bfhi(ff[t].y) * wg;
            acc[4] += bflo(ff[t].z) * wg; acc[5] += bfhi(ff[t].z) * wg;
            acc[6] += bflo(ff[t].w) * wg; acc[7] += bfhi(ff[t].w) * wg;
        }
    }

    // reduce across the 4 edge subsets (lane bits 2,3)
    d += __shfl_xor(d, 4, 64);
    d += __shfl_xor(d, 8, 64);
#pragma unroll
    for (int k = 0; k < 8; k++) {
        acc[k] += __shfl_xor(acc[k], 4, 64);
        acc[k] += __shfl_xor(acc[k], 8, 64);
    }

    float invd = 1.f / fmaxf(d, 1e-9f);
#pragma unroll
    for (int k = 0; k < 8; k++) acc[k] *= invd;

    // ---- epilogue: this lane owns 8 channels at coff of node n ----
    float rr[8];
    if (residf) {
        float4 r0 = *(const float4*)(residf + (size_t)n * 256 + coff);
        float4 r1 = *(const float4*)(residf + (size_t)n * 256 + coff + 4);
        rr[0] = r0.x; rr[1] = r0.y; rr[2] = r0.z; rr[3] = r0.w;
        rr[4] = r1.x; rr[5] = r1.y; rr[6] = r1.z; rr[7] = r1.w;
    } else {
        uint4 rv = *(const uint4*)(residh + (size_t)n * 256 + coff);
        rr[0] = bflo(rv.x); rr[1] = bfhi(rv.x);
        rr[2] = bflo(rv.y); rr[3] = bfhi(rv.y);
        rr[4] = bflo(rv.z); rr[5] = bfhi(rv.z);
        rr[6] = bflo(rv.w); rr[7] = bfhi(rv.w);
    }
    if (use_bn) {
        float4 s0 = *(const float4*)(bnscale + coff);
        float4 s1 = *(const float4*)(bnscale + coff + 4);
        float4 h0 = *(const float4*)(bnshift + coff);
        float4 h1 = *(const float4*)(bnshift + coff + 4);
        rr[0] = rr[0] * s0.x + h0.x; rr[1] = rr[1] * s0.y + h0.y;
        rr[2] = rr[2] * s0.z + h0.z; rr[3] = rr[3] * s0.w + h0.w;
        rr[4] = rr[4] * s1.x + h1.x; rr[5] = rr[5] * s1.y + h1.y;
        rr[6] = rr[6] * s1.z + h1.z; rr[7] = rr[7] * s1.w + h1.w;
    }
    {
        float4 b0 = *(const float4*)(bias + coff);
        float4 b1 = *(const float4*)(bias + coff + 4);
        acc[0] += rr[0] + b0.x; acc[1] += rr[1] + b0.y;
        acc[2] += rr[2] + b0.z; acc[3] += rr[3] + b0.w;
        acc[4] += rr[4] + b1.x; acc[5] += rr[5] + b1.y;
        acc[6] += rr[6] + b1.z; acc[7] += rr[7] + b1.w;
    }
    if (act) {
#pragma unroll
        for (int k = 0; k < 8; k++) acc[k] = (acc[k] > 0.f) ? acc[k] : SLOPE_R * acc[k];
    }

    if (es == 0) {   // one lane per (node, chunk) commits
        if (!final_mean) {
            uint4 o;
            o.x = (unsigned)f2bf(acc[0]) | ((unsigned)f2bf(acc[1]) << 16);
            o.y = (unsigned)f2bf(acc[2]) | ((unsigned)f2bf(acc[3]) << 16);
            o.z = (unsigned)f2bf(acc[4]) | ((unsigned)f2bf(acc[5]) << 16);
            o.w = (unsigned)f2bf(acc[6]) | ((unsigned)f2bf(acc[7]) << 16);
            *(uint4*)(outh + (size_t)n * 256 + coff) = o;
        } else {
            // head mean: heads live on different slices -> atomic accumulate
            int dd = (slice & 1) * 32 + ck * 8;
#pragma unroll
            for (int k = 0; k < 8; k++)
                atomicAdd(outf + (size_t)n * 64 + dd + k, 0.25f * acc[k]);
        }
    }
}

// ---------------- BatchNorm stats: vectorized partials, no atomics (256 blocks) ----
__global__ void k_bnstats(const unsigned short* __restrict__ hh, float* __restrict__ pbuf) {
    __shared__ float ps[8 * 256];
    __shared__ float ps2[8 * 256];
    int t = threadIdx.x, b = blockIdx.x;
    int r8 = t >> 5, c32 = t & 31;
    int r0 = b * 196, r1 = min(r0 + 196, NN);
    float s[8], s2[8];
#pragma unroll
    for (int e = 0; e < 8; e++) { s[e] = 0.f; s2[e] = 0.f; }
    for (int r = r0 + r8; r < r1; r += 8) {
        uint4 v = *(const uint4*)(hh + (size_t)r * 256 + c32 * 8);
        const unsigned short* pv = (const unsigned short*)&v;
#pragma unroll
        for (int e = 0; e < 8; e++) {
            float f = bf2f(pv[e]);
            s[e] += f; s2[e] += f * f;
        }
    }
#pragma unroll
    for (int e = 0; e < 8; e++) {
        ps[r8 * 256 + c32 * 8 + e] = s[e];
        ps2[r8 * 256 + c32 * 8 + e] = s2[e];
    }
    __syncthreads();
    float ts = 0.f, ts2 = 0.f;
    for (int g = 0; g < 8; g++) { ts += ps[g * 256 + t]; ts2 += ps2[g * 256 + t]; }
    pbuf[b * 512 + t] = ts;
    pbuf[b * 512 + 256 + t] = ts2;
}

__global__ void k_bnfinal(const float* __restrict__ pbuf, const float* __restrict__ g,
                          const float* __restrict__ be, float* __restrict__ scale,
                          float* __restrict__ shift) {
    int t = threadIdx.x;
    float s = 0.f, s2 = 0.f;
    for (int b = 0; b < 256; b++) {
        s += pbuf[b * 512 + t];
        s2 += pbuf[b * 512 + 256 + t];
    }
    float mu = s * (1.f / NN);
    float var = s2 * (1.f / NN) - mu * mu;
    float rs = rsqrtf(var + 1e-5f);
    float sc = rs * g[t];
    scale[t] = sc;
    shift[t] = be[t] - mu * sc;
}

// ---------------- launcher ----------------
extern "C" void kernel_launch(void* const* d_in, const int* in_sizes, int n_in,
                              void* d_out, int out_size, void* d_ws, size_t ws_size,
                              hipStream_t stream) {
    const float* x   = (const float*)d_in[0];
    const int* src   = (const int*)d_in[1];
    const int* dst   = (const int*)d_in[2];
    const float* W1  = (const float*)d_in[3];
    const float* al1 = (const float*)d_in[4];
    const float* ar1 = (const float*)d_in[5];
    const float* b1  = (const float*)d_in[6];
    const float* W2  = (const float*)d_in[7];
    const float* al2 = (const float*)d_in[8];
    const float* ar2 = (const float*)d_in[9];
    const float* b2  = (const float*)d_in[10];
    const float* W3  = (const float*)d_in[11];
    const float* al3 = (const float*)d_in[12];
    const float* ar3 = (const float*)d_in[13];
    const float* b3  = (const float*)d_in[14];
    const float* g1  = (const float*)d_in[15];
    const float* be1 = (const float*)d_in[16];
    const float* g2  = (const float*)d_in[17];
    const float* be2 = (const float*)d_in[18];
    float* out = (float*)d_out;

    char* ws = (char*)d_ws;
    size_t off = 0;
    auto alloc = [&](size_t bytes) {
        void* p = ws + off;
        off += (bytes + 255) & ~(size_t)255;
        return p;
    };
    int* rowptr = (int*)alloc((NN + 1) * sizeof(int));
    int* cursor = (int*)alloc(NN * sizeof(int));
    int* cnt    = (int*)alloc(SCB * 256 * sizeof(int));
    int* loc    = (int*)alloc(SCB * 256 * sizeof(int));
    int* bsum   = (int*)alloc(SCB * sizeof(int));
    int* boff   = (int*)alloc(SCB * sizeof(int));
    unsigned short* ssrc = (unsigned short*)alloc(NE * sizeof(unsigned short));
    unsigned short* feat16 = (unsigned short*)alloc((size_t)NN * 256 * sizeof(unsigned short));
    unsigned short* hbuf   = (unsigned short*)alloc((size_t)NN * 256 * sizeof(unsigned short));
    float* el   = (float*)alloc((size_t)NN * 4 * sizeof(float));
    float* er   = (float*)alloc((size_t)NN * 4 * sizeof(float));
    unsigned short* Wfrag1  = (unsigned short*)alloc(65536 * sizeof(unsigned short));
    unsigned short* Wfrag2  = (unsigned short*)alloc(65536 * sizeof(unsigned short));
    unsigned short* wlrfrag = (unsigned short*)alloc(4096 * sizeof(unsigned short));
    float* offlr   = (float*)alloc(16 * sizeof(float));
    float* cvec    = (float*)alloc(256 * sizeof(float));
    float* pbuf    = (float*)alloc(256 * 512 * sizeof(float));
    float* bnscale = (float*)alloc(256 * sizeof(float));
    float* bnshift = (float*)alloc(256 * sizeof(float));

    // CSR build (graph identical for all layers)
    hipMemsetAsync(cnt, 0, NN * sizeof(int), stream);
    k_hist<<<(NE + 255) / 256, 256, 0, stream>>>(dst, cnt);
    k_scan1<<<SCB, 256, 0, stream>>>(cnt, loc, bsum);
    k_scan2<<<1, 256, 0, stream>>>(bsum, boff, rowptr);
    k_scan3<<<SCB, 256, 0, stream>>>(loc, boff, rowptr, cursor);
    k_scatter<<<(NE + 255) / 256, 256, 0, stream>>>(src, dst, cursor, ssrc);
    k_fold<<<40, 256, 0, stream>>>(W1, nullptr, nullptr, al1, ar1,
                                   Wfrag1, nullptr, wlrfrag, offlr, 0);
    // zero the final output (accumulated via atomics from the 8 slices)
    hipMemsetAsync(out, 0, (size_t)NN * 64 * sizeof(float), stream);

    const int GB = (NN + 63) / 64;   // 782
    const int AB = 8 * (NN / 16);    // 25000 slice-blocks

    // ---- layer 1 ----
    k_gemm<<<GB, 256, 0, stream>>>(x, 1, Wfrag1, nullptr, wlrfrag, offlr, feat16, el, er);
    k_aggs<<<AB, 256, 0, stream>>>(feat16, el, er, rowptr, ssrc, nullptr, x,
                                   nullptr, nullptr, 0, b1, 1, hbuf, nullptr, 0);
    k_bnstats<<<256, 256, 0, stream>>>(hbuf, pbuf);
    k_bnfinal<<<1, 256, 0, stream>>>(pbuf, g1, be1, bnscale, bnshift);
    k_fold<<<296, 256, 0, stream>>>(W2, bnscale, bnshift, al2, ar2,
                                    Wfrag2, cvec, wlrfrag, offlr, 1);

    // ---- layer 2 ----
    k_gemm<<<GB, 256, 0, stream>>>(hbuf, 0, Wfrag2, cvec, wlrfrag, offlr, feat16, el, er);
    k_aggs<<<AB, 256, 0, stream>>>(feat16, el, er, rowptr, ssrc, hbuf, nullptr,
                                   bnscale, bnshift, 1, b2, 1, hbuf, nullptr, 0);
    k_bnstats<<<256, 256, 0, stream>>>(hbuf, pbuf);
    k_bnfinal<<<1, 256, 0, stream>>>(pbuf, g2, be2, bnscale, bnshift);
    k_fold<<<296, 256, 0, stream>>>(W3, bnscale, bnshift, al3, ar3,
                                    Wfrag2, cvec, wlrfrag, offlr, 1);

    // ---- layer 3 ----
    k_gemm<<<GB, 256, 0, stream>>>(hbuf, 0, Wfrag2, cvec, wlrfrag, offlr, feat16, el, er);
    k_aggs<<<AB, 256, 0, stream>>>(feat16, el, er, rowptr, ssrc, hbuf, nullptr,
                                   bnscale, bnshift, 1, b3, 0, nullptr, out, 1);
}

// Round 5
// 544.944 us; speedup vs baseline: 1.6180x; 1.6180x over previous
//
#include <hip/hip_runtime.h>

constexpr int NN = 50000;     // nodes
constexpr int NE = 800000;    // edges
constexpr float SLOPE_A = 0.2f;   // attention leaky_relu
constexpr float SLOPE_R = 0.01f;  // activation leaky_relu
constexpr int SCB = 196;      // scan blocks: 196*256 = 50176 >= NN

typedef __attribute__((ext_vector_type(8))) short bf16x8;
typedef __attribute__((ext_vector_type(4))) float f32x4;

__device__ __forceinline__ unsigned short f2bf(float f) {
    union { float f; unsigned u; } v; v.f = f;
    unsigned u = v.u;
    unsigned r = u + 0x7fffu + ((u >> 16) & 1u);  // round-to-nearest-even
    return (unsigned short)(r >> 16);
}
__device__ __forceinline__ float bf2f(unsigned short s) {
    union { unsigned u; float f; } v; v.u = ((unsigned)s) << 16;
    return v.f;
}
// low/high bf16 halves of a packed u32 -> f32 (1 VALU op each)
__device__ __forceinline__ float bflo(unsigned u) {
    union { unsigned u; float f; } v; v.u = u << 16; return v.f;
}
__device__ __forceinline__ float bfhi(unsigned u) {
    union { unsigned u; float f; } v; v.u = u & 0xffff0000u; return v.f;
}

// ---------------- CSR build ----------------
__global__ void k_hist(const int* __restrict__ dst, int* __restrict__ cnt) {
    int i = blockIdx.x * 256 + threadIdx.x;
    if (i < NE) atomicAdd(&cnt[dst[i]], 1);
}

__global__ void k_scan1(const int* __restrict__ cnt, int* __restrict__ loc,
                        int* __restrict__ bsum) {
    __shared__ int sh[256];
    int t = threadIdx.x;
    int i = blockIdx.x * 256 + t;
    int v = (i < NN) ? cnt[i] : 0;
    sh[t] = v;
    __syncthreads();
    for (int off = 1; off < 256; off <<= 1) {
        int tmp = (t >= off) ? sh[t - off] : 0;
        __syncthreads();
        sh[t] += tmp;
        __syncthreads();
    }
    loc[i] = sh[t] - v;
    if (t == 255) bsum[blockIdx.x] = sh[255];
}

__global__ void k_scan2(const int* __restrict__ bsum, int* __restrict__ boff,
                        int* __restrict__ rowptr) {
    __shared__ int sh[256];
    int t = threadIdx.x;
    int v = (t < SCB) ? bsum[t] : 0;
    sh[t] = v;
    __syncthreads();
    for (int off = 1; off < 256; off <<= 1) {
        int tmp = (t >= off) ? sh[t - off] : 0;
        __syncthreads();
        sh[t] += tmp;
        __syncthreads();
    }
    if (t < SCB) boff[t] = sh[t] - v;
    if (t == 255) rowptr[NN] = sh[255];
}

__global__ void k_scan3(const int* __restrict__ loc, const int* __restrict__ boff,
                        int* __restrict__ rowptr, int* __restrict__ cursor) {
    int i = blockIdx.x * 256 + threadIdx.x;
    if (i < NN) {
        int r = loc[i] + boff[blockIdx.x];
        rowptr[i] = r;
        cursor[i] = r;
    }
}

// src ids fit in 16 bits (NN < 65536): halves the sorted-src index stream
__global__ void k_scatter(const int* __restrict__ src, const int* __restrict__ dst,
                          int* __restrict__ cursor, unsigned short* __restrict__ ssrc) {
    int i = blockIdx.x * 256 + threadIdx.x;
    if (i < NE) {
        int d = dst[i];
        int pos = atomicAdd(&cursor[d], 1);
        ssrc[pos] = (unsigned short)src[i];
    }
}

// ---------------- fold: Wfrag + cvec + wl/wr fragment + offlr, all from fp32 W ----
// has_bn=1 grid 296: b<32 Wfrag | 32..287 cvec | 288..295 lr-fold (n=b-288)
// has_bn=0 grid  40: b<32 Wfrag | 32..39 lr-fold (n=b-32)
__global__ void k_fold(const float* __restrict__ W, const float* __restrict__ sc,
                       const float* __restrict__ sh, const float* __restrict__ al,
                       const float* __restrict__ ar, unsigned short* __restrict__ Wfrag,
                       float* __restrict__ cvec, unsigned short* __restrict__ wlrfrag,
                       float* __restrict__ offlr, int has_bn) {
    int b = blockIdx.x;
    if (b < 32) {
        int gid = b * 256 + threadIdx.x;   // < 8192; one thread = 8 shorts
        int lane = gid & 63;
        int frag = gid >> 6;               // 0..127
        int j = frag & 3, kc = (frag >> 2) & 7, w = frag >> 5;
        int mm = lane & 15, q = lane >> 4;
        int n = 64 * w + 16 * j + mm;
        int k0 = kc * 32 + q * 8;
        unsigned short o[8];
#pragma unroll
        for (int t = 0; t < 8; t++) {
            float wv = W[(size_t)(k0 + t) * 256 + n];
            if (sc) wv *= sc[k0 + t];
            o[t] = f2bf(wv);
        }
        *(uint4*)(Wfrag + (size_t)gid * 8) = *(const uint4*)o;
    } else if (has_bn && b < 288) {
        __shared__ float red[256];
        int n = b - 32, k = threadIdx.x;
        red[k] = sh[k] * W[(size_t)k * 256 + n];
        __syncthreads();
        for (int off = 128; off > 0; off >>= 1) {
            if (k < off) red[k] += red[k + off];
            __syncthreads();
        }
        if (k == 0) cvec[n] = red[0];
    } else {
        int n = b - (has_bn ? 288 : 32);   // 0..7
        int h = n >> 1;
        const float* a = (n & 1) ? ar : al;
        int k = threadIdx.x;
        float raw = 0.f;
#pragma unroll 8
        for (int d = 0; d < 64; d++)
            raw += W[(size_t)k * 256 + 64 * h + d] * a[h * 64 + d];
        float val = (sc ? sc[k] : 1.f) * raw;
        int kc = k >> 5, rem = k & 31, q = rem >> 3, t = rem & 7;  // k = kc*32+q*8+t
        wlrfrag[kc * 512 + (q * 16 + n) * 8 + t] = f2bf(val);
        wlrfrag[kc * 512 + (q * 16 + n + 8) * 8 + t] = 0;   // zero the unused col
        __shared__ float red[256];
        red[k] = sh ? sh[k] * raw : 0.f;
        __syncthreads();
        for (int off = 128; off > 0; off >>= 1) {
            if (k < off) red[k] += red[k + off];
            __syncthreads();
        }
        if (k == 0) offlr[n] = red[0];
    }
}

// ---------------- GEMM: feat = A @ Wfrag (+cvec); el/er via extra MFMA --------
// block: 256 thr = 4 waves; tile 64 rows x 256 cols; wave w owns cols [64w,64w+64).
// Wave 0 additionally computes the 8-col el/er matvec with one extra B-frag.
__launch_bounds__(256)
__global__ void k_gemm(const void* __restrict__ Araw, int af32,
                       const unsigned short* __restrict__ Wfrag,
                       const float* __restrict__ cvec,
                       const unsigned short* __restrict__ wlrfrag,
                       const float* __restrict__ offlr,
                       unsigned short* __restrict__ feat16, float* __restrict__ el,
                       float* __restrict__ er) {
    constexpr int AP = 264;  // A lds pitch in bf16 elems (row start 16B-aligned)
    __shared__ __align__(16) unsigned short Alds[64 * AP];
    const int tid = threadIdx.x;
    const int rowbase = blockIdx.x * 64;

    // stage A: 64 rows x 256 bf16
    if (af32) {
        const float* A = (const float*)Araw;
        int r = tid >> 6;
        int c4 = tid & 63;
        for (int it = 0; it < 16; it++) {
            int rr = it * 4 + r;
            int gr = rowbase + rr;
            float4 v = make_float4(0.f, 0.f, 0.f, 0.f);
            if (gr < NN) v = *(const float4*)(A + (size_t)gr * 256 + c4 * 4);
            ushort4 pv;
            pv.x = f2bf(v.x); pv.y = f2bf(v.y); pv.z = f2bf(v.z); pv.w = f2bf(v.w);
            *(ushort4*)(&Alds[rr * AP + c4 * 4]) = pv;
        }
    } else {
        const unsigned short* A = (const unsigned short*)Araw;
        for (int it = 0; it < 8; it++) {
            int idx = it * 256 + tid;
            int rr = idx >> 5;
            int c16 = idx & 31;
            int gr = rowbase + rr;
            uint4 v = make_uint4(0u, 0u, 0u, 0u);
            if (gr < NN) v = *(const uint4*)(A + (size_t)gr * 256 + c16 * 8);
            *(uint4*)(&Alds[rr * AP + c16 * 8]) = v;
        }
    }
    __syncthreads();

    f32x4 acc[4][4];
    for (int i = 0; i < 4; i++)
        for (int j = 0; j < 4; j++)
            acc[i][j] = (f32x4){0.f, 0.f, 0.f, 0.f};
    f32x4 accLR[4];
    for (int i = 0; i < 4; i++) accLR[i] = (f32x4){0.f, 0.f, 0.f, 0.f};

    const int lane = tid & 63, w = tid >> 6;
    const int mm = lane & 15, q = lane >> 4;

    const unsigned short* bbase = Wfrag + ((size_t)w * 8 * 4) * 512 + (size_t)lane * 8;

#pragma unroll
    for (int kc = 0; kc < 8; kc++) {
        bf16x8 a[4], b[4];
        for (int i = 0; i < 4; i++)
            a[i] = *(const bf16x8*)(&Alds[(16 * i + mm) * AP + kc * 32 + q * 8]);
        for (int j = 0; j < 4; j++)
            b[j] = *(const bf16x8*)(bbase + (size_t)(kc * 4 + j) * 512);
        for (int i = 0; i < 4; i++)
            for (int j = 0; j < 4; j++)
                acc[i][j] = __builtin_amdgcn_mfma_f32_16x16x32_bf16(a[i], b[j], acc[i][j], 0, 0, 0);
        if (w == 0) {
            bf16x8 blr = *(const bf16x8*)(wlrfrag + kc * 512 + lane * 8);
            for (int i = 0; i < 4; i++)
                accLR[i] = __builtin_amdgcn_mfma_f32_16x16x32_bf16(a[i], blr, accLR[i], 0, 0, 0);
        }
    }
    __syncthreads();   // all waves done reading Alds before epilogue reuses it

    // ---- folded-BN column offset on feat ----
    if (cvec) {
        float cv[4];
        for (int j = 0; j < 4; j++) cv[j] = cvec[64 * w + 16 * j + mm];
        for (int i = 0; i < 4; i++)
            for (int j = 0; j < 4; j++)
                for (int r = 0; r < 4; r++)
                    acc[i][j][r] += cv[j];
    }

    // ---- el/er write (wave 0, C-layout col=mm -> n=2h+s) ----
    if (w == 0 && mm < 8) {
        float off = offlr[mm];
        int h = mm >> 1;
        float* dstp = (mm & 1) ? er : el;
        for (int i = 0; i < 4; i++)
            for (int r = 0; r < 4; r++) {
                int gr = rowbase + 16 * i + q * 4 + r;
                if (gr < NN) dstp[gr * 4 + h] = accLR[i][r] + off;
            }
    }

    // ---- LDS-bounce feat16 store (C/D layout: col=lane&15, row=(lane>>4)*4+reg) ----
    for (int i = 0; i < 4; i++)
        for (int j = 0; j < 4; j++) {
            int gc = 64 * w + 16 * j + mm;
            for (int r = 0; r < 4; r++) {
                int rr = 16 * i + q * 4 + r;
                Alds[rr * AP + gc] = f2bf(acc[i][j][r]);
            }
        }
    __syncthreads();
    for (int it = 0; it < 8; it++) {
        int idx = it * 256 + tid;
        int rr = idx >> 5;
        int c16 = idx & 31;
        int gr = rowbase + rr;
        if (gr < NN)
            *(uint4*)(feat16 + (size_t)gr * 256 + c16 * 8) = *(const uint4*)(&Alds[rr * AP + c16 * 8]);
    }
}

// ---------------- per-dst softmax + weighted aggregation (bf16 gather) ----------------
// ONE wave per destination node; R1-proven structure (3.74 TB/s effective).
// Lane l: edge parity p = l>>5, channel group q = l&31 (8 ch, 16B gathers).
// Per 8-edge chunk: 4 direct-addressed 16B feat gathers in flight per lane.
// Attention weight computed INLINE per lane (el gather + exp, redundant x8 per
// head): redundancy is free (R0 evidence), and no wgt stream bytes, no
// cross-lane ops anywhere in the loop (R2/R3 lesson).
__launch_bounds__(256)
__global__ void k_agg(const unsigned short* __restrict__ feat16,
                      const float* __restrict__ el, const float* __restrict__ er,
                      const int* __restrict__ rowptr, const unsigned short* __restrict__ ssrc,
                      const unsigned short* __restrict__ residh, const float* __restrict__ residf,
                      const float* __restrict__ bnscale, const float* __restrict__ bnshift,
                      int use_bn, const float* __restrict__ bias, int act,
                      unsigned short* __restrict__ outh, float* __restrict__ outf,
                      int final_mean) {
    int n = __builtin_amdgcn_readfirstlane(blockIdx.x * 4 + (threadIdx.x >> 6));
    int l = threadIdx.x & 63;
    int p = l >> 5;            // edge parity
    int q = l & 31;            // channel group
    int c8 = q * 8;            // channels [c8, c8+8)
    int hh = q >> 3;           // head of this channel group
    int beg = rowptr[n], end = rowptr[n + 1];
    float erh = er[n * 4 + hh];

    // hoisted epilogue operands (issue loads early, consume after the loop)
    float r[8];
    if (residf) {
        float4 r0 = *(const float4*)(residf + (size_t)n * 256 + c8);
        float4 r1 = *(const float4*)(residf + (size_t)n * 256 + c8 + 4);
        r[0] = r0.x; r[1] = r0.y; r[2] = r0.z; r[3] = r0.w;
        r[4] = r1.x; r[5] = r1.y; r[6] = r1.z; r[7] = r1.w;
    } else {
        uint4 rv = *(const uint4*)(residh + (size_t)n * 256 + c8);
        r[0] = bflo(rv.x); r[1] = bfhi(rv.x);
        r[2] = bflo(rv.y); r[3] = bfhi(rv.y);
        r[4] = bflo(rv.z); r[5] = bfhi(rv.z);
        r[6] = bflo(rv.w); r[7] = bfhi(rv.w);
    }

    float d = 0.f;
    float acc[8];
#pragma unroll
    for (int k = 0; k < 8; k++) acc[k] = 0.f;

    for (int e = beg; e < end; e += 8) {
        int ss[4];
#pragma unroll
        for (int j = 0; j < 4; j++) {
            int idx = e + 2 * j + p;
            ss[j] = ssrc[(idx < end) ? idx : beg];
        }
        float aa[4];
#pragma unroll
        for (int j = 0; j < 4; j++)
            aa[j] = el[ss[j] * 4 + hh];
        uint4 ff[4];
#pragma unroll
        for (int j = 0; j < 4; j++)
            ff[j] = *(const uint4*)(feat16 + (size_t)ss[j] * 256 + c8);
#pragma unroll
        for (int j = 0; j < 4; j++) {
            float sc = aa[j] + erh;
            sc = (sc > 0.f) ? sc : SLOPE_A * sc;
            float w = ((e + 2 * j + p) < end) ? __expf(sc) : 0.f;
            d += w;
            acc[0] += bflo(ff[j].x) * w; acc[1] += bfhi(ff[j].x) * w;
            acc[2] += bflo(ff[j].y) * w; acc[3] += bfhi(ff[j].y) * w;
            acc[4] += bflo(ff[j].z) * w; acc[5] += bfhi(ff[j].z) * w;
            acc[6] += bflo(ff[j].w) * w; acc[7] += bfhi(ff[j].w) * w;
        }
    }

    // combine edge parities
    d += __shfl_xor(d, 32, 64);
#pragma unroll
    for (int k = 0; k < 8; k++) acc[k] += __shfl_xor(acc[k], 32, 64);

    float invd = 1.f / fmaxf(d, 1e-9f);
#pragma unroll
    for (int k = 0; k < 8; k++) acc[k] *= invd;

    if (use_bn) {
        float4 s0 = *(const float4*)(bnscale + c8);
        float4 s1 = *(const float4*)(bnscale + c8 + 4);
        float4 h0 = *(const float4*)(bnshift + c8);
        float4 h1 = *(const float4*)(bnshift + c8 + 4);
        r[0] = r[0] * s0.x + h0.x; r[1] = r[1] * s0.y + h0.y;
        r[2] = r[2] * s0.z + h0.z; r[3] = r[3] * s0.w + h0.w;
        r[4] = r[4] * s1.x + h1.x; r[5] = r[5] * s1.y + h1.y;
        r[6] = r[6] * s1.z + h1.z; r[7] = r[7] * s1.w + h1.w;
    }
    {
        float4 b0 = *(const float4*)(bias + c8);
        float4 b1 = *(const float4*)(bias + c8 + 4);
        acc[0] += r[0] + b0.x; acc[1] += r[1] + b0.y;
        acc[2] += r[2] + b0.z; acc[3] += r[3] + b0.w;
        acc[4] += r[4] + b1.x; acc[5] += r[5] + b1.y;
        acc[6] += r[6] + b1.z; acc[7] += r[7] + b1.w;
    }
    if (act) {
#pragma unroll
        for (int k = 0; k < 8; k++) acc[k] = (acc[k] > 0.f) ? acc[k] : SLOPE_R * acc[k];
    }

    if (!final_mean) {
        if (p == 0) {
            uint4 o;
            o.x = (unsigned)f2bf(acc[0]) | ((unsigned)f2bf(acc[1]) << 16);
            o.y = (unsigned)f2bf(acc[2]) | ((unsigned)f2bf(acc[3]) << 16);
            o.z = (unsigned)f2bf(acc[4]) | ((unsigned)f2bf(acc[5]) << 16);
            o.w = (unsigned)f2bf(acc[6]) | ((unsigned)f2bf(acc[7]) << 16);
            *(uint4*)(outh + (size_t)n * 256 + c8) = o;
        }
    } else {
        // head mean: lanes q, q^8, q^16(,q^24) hold same d-channel, different heads
#pragma unroll
        for (int k = 0; k < 8; k++) {
            acc[k] += __shfl_xor(acc[k], 8, 64);
            acc[k] += __shfl_xor(acc[k], 16, 64);
        }
        if (p == 0 && q < 8) {
            float4 o0 = make_float4(acc[0] * 0.25f, acc[1] * 0.25f, acc[2] * 0.25f, acc[3] * 0.25f);
            float4 o1 = make_float4(acc[4] * 0.25f, acc[5] * 0.25f, acc[6] * 0.25f, acc[7] * 0.25f);
            *(float4*)(outf + (size_t)n * 64 + c8) = o0;
            *(float4*)(outf + (size_t)n * 64 + c8 + 4) = o1;
        }
    }
}

// ---------------- BatchNorm stats: vectorized partials, no atomics (256 blocks) ----
__global__ void k_bnstats(const unsigned short* __restrict__ hh, float* __restrict__ pbuf) {
    __shared__ float ps[8 * 256];
    __shared__ float ps2[8 * 256];
    int t = threadIdx.x, b = blockIdx.x;
    int r8 = t >> 5, c32 = t & 31;
    int r0 = b * 196, r1 = min(r0 + 196, NN);
    float s[8], s2[8];
#pragma unroll
    for (int e = 0; e < 8; e++) { s[e] = 0.f; s2[e] = 0.f; }
    for (int r = r0 + r8; r < r1; r += 8) {
        uint4 v = *(const uint4*)(hh + (size_t)r * 256 + c32 * 8);
        const unsigned short* pv = (const unsigned short*)&v;
#pragma unroll
        for (int e = 0; e < 8; e++) {
            float f = bf2f(pv[e]);
            s[e] += f; s2[e] += f * f;
        }
    }
#pragma unroll
    for (int e = 0; e < 8; e++) {
        ps[r8 * 256 + c32 * 8 + e] = s[e];
        ps2[r8 * 256 + c32 * 8 + e] = s2[e];
    }
    __syncthreads();
    float ts = 0.f, ts2 = 0.f;
    for (int g = 0; g < 8; g++) { ts += ps[g * 256 + t]; ts2 += ps2[g * 256 + t]; }
    pbuf[b * 512 + t] = ts;
    pbuf[b * 512 + 256 + t] = ts2;
}

__global__ void k_bnfinal(const float* __restrict__ pbuf, const float* __restrict__ g,
                          const float* __restrict__ be, float* __restrict__ scale,
                          float* __restrict__ shift) {
    int t = threadIdx.x;
    float s = 0.f, s2 = 0.f;
    for (int b = 0; b < 256; b++) {
        s += pbuf[b * 512 + t];
        s2 += pbuf[b * 512 + 256 + t];
    }
    float mu = s * (1.f / NN);
    float var = s2 * (1.f / NN) - mu * mu;
    float rs = rsqrtf(var + 1e-5f);
    float sc = rs * g[t];
    scale[t] = sc;
    shift[t] = be[t] - mu * sc;
}

// ---------------- launcher ----------------
extern "C" void kernel_launch(void* const* d_in, const int* in_sizes, int n_in,
                              void* d_out, int out_size, void* d_ws, size_t ws_size,
                              hipStream_t stream) {
    const float* x   = (const float*)d_in[0];
    const int* src   = (const int*)d_in[1];
    const int* dst   = (const int*)d_in[2];
    const float* W1  = (const float*)d_in[3];
    const float* al1 = (const float*)d_in[4];
    const float* ar1 = (const float*)d_in[5];
    const float* b1  = (const float*)d_in[6];
    const float* W2  = (const float*)d_in[7];
    const float* al2 = (const float*)d_in[8];
    const float* ar2 = (const float*)d_in[9];
    const float* b2  = (const float*)d_in[10];
    const float* W3  = (const float*)d_in[11];
    const float* al3 = (const float*)d_in[12];
    const float* ar3 = (const float*)d_in[13];
    const float* b3  = (const float*)d_in[14];
    const float* g1  = (const float*)d_in[15];
    const float* be1 = (const float*)d_in[16];
    const float* g2  = (const float*)d_in[17];
    const float* be2 = (const float*)d_in[18];
    float* out = (float*)d_out;

    char* ws = (char*)d_ws;
    size_t off = 0;
    auto alloc = [&](size_t bytes) {
        void* p = ws + off;
        off += (bytes + 255) & ~(size_t)255;
        return p;
    };
    int* rowptr = (int*)alloc((NN + 1) * sizeof(int));
    int* cursor = (int*)alloc(NN * sizeof(int));
    int* cnt    = (int*)alloc(SCB * 256 * sizeof(int));
    int* loc    = (int*)alloc(SCB * 256 * sizeof(int));
    int* bsum   = (int*)alloc(SCB * sizeof(int));
    int* boff   = (int*)alloc(SCB * sizeof(int));
    unsigned short* ssrc = (unsigned short*)alloc(NE * sizeof(unsigned short));
    unsigned short* feat16 = (unsigned short*)alloc((size_t)NN * 256 * sizeof(unsigned short));
    unsigned short* hbuf   = (unsigned short*)alloc((size_t)NN * 256 * sizeof(unsigned short));
    float* el   = (float*)alloc((size_t)NN * 4 * sizeof(float));
    float* er   = (float*)alloc((size_t)NN * 4 * sizeof(float));
    unsigned short* Wfrag1  = (unsigned short*)alloc(65536 * sizeof(unsigned short));
    unsigned short* Wfrag2  = (unsigned short*)alloc(65536 * sizeof(unsigned short));
    unsigned short* wlrfrag = (unsigned short*)alloc(4096 * sizeof(unsigned short));
    float* offlr   = (float*)alloc(16 * sizeof(float));
    float* cvec    = (float*)alloc(256 * sizeof(float));
    float* pbuf    = (float*)alloc(256 * 512 * sizeof(float));
    float* bnscale = (float*)alloc(256 * sizeof(float));
    float* bnshift = (float*)alloc(256 * sizeof(float));

    // CSR build (graph identical for all layers)
    hipMemsetAsync(cnt, 0, NN * sizeof(int), stream);
    k_hist<<<(NE + 255) / 256, 256, 0, stream>>>(dst, cnt);
    k_scan1<<<SCB, 256, 0, stream>>>(cnt, loc, bsum);
    k_scan2<<<1, 256, 0, stream>>>(bsum, boff, rowptr);
    k_scan3<<<SCB, 256, 0, stream>>>(loc, boff, rowptr, cursor);
    k_scatter<<<(NE + 255) / 256, 256, 0, stream>>>(src, dst, cursor, ssrc);
    k_fold<<<40, 256, 0, stream>>>(W1, nullptr, nullptr, al1, ar1,
                                   Wfrag1, nullptr, wlrfrag, offlr, 0);

    const int GB = (NN + 63) / 64;  // 782
    const int NB = NN / 4;          // 12500

    // ---- layer 1 ----
    k_gemm<<<GB, 256, 0, stream>>>(x, 1, Wfrag1, nullptr, wlrfrag, offlr, feat16, el, er);
    k_agg<<<NB, 256, 0, stream>>>(feat16, el, er, rowptr, ssrc, nullptr, x,
                                  nullptr, nullptr, 0, b1, 1, hbuf, nullptr, 0);
    k_bnstats<<<256, 256, 0, stream>>>(hbuf, pbuf);
    k_bnfinal<<<1, 256, 0, stream>>>(pbuf, g1, be1, bnscale, bnshift);
    k_fold<<<296, 256, 0, stream>>>(W2, bnscale, bnshift, al2, ar2,
                                    Wfrag2, cvec, wlrfrag, offlr, 1);

    // ---- layer 2 ----
    k_gemm<<<GB, 256, 0, stream>>>(hbuf, 0, Wfrag2, cvec, wlrfrag, offlr, feat16, el, er);
    k_agg<<<NB, 256, 0, stream>>>(feat16, el, er, rowptr, ssrc, hbuf, nullptr,
                                  bnscale, bnshift, 1, b2, 1, hbuf, nullptr, 0);
    k_bnstats<<<256, 256, 0, stream>>>(hbuf, pbuf);
    k_bnfinal<<<1, 256, 0, stream>>>(pbuf, g2, be2, bnscale, bnshift);
    k_fold<<<296, 256, 0, stream>>>(W3, bnscale, bnshift, al3, ar3,
                                    Wfrag2, cvec, wlrfrag, offlr, 1);

    // ---- layer 3 ----
    k_gemm<<<GB, 256, 0, stream>>>(hbuf, 0, Wfrag2, cvec, wlrfrag, offlr, feat16, el, er);
    k_agg<<<NB, 256, 0, stream>>>(feat16, el, er, rowptr, ssrc, hbuf, nullptr,
                                  bnscale, bnshift, 1, b3, 0, nullptr, out, 1);
}